// Round 8
// baseline (239.551 us; speedup 1.0000x reference)
//
#include <hip/hip_runtime.h>
#include <hip/hip_bf16.h>
#include <math.h>

typedef __hip_bfloat16 bf16;
typedef __attribute__((ext_vector_type(8))) short bf16x8;
typedef __attribute__((ext_vector_type(4))) float f32x4;
typedef __attribute__((ext_vector_type(8))) int i32x8;
typedef __attribute__((ext_vector_type(4))) int i32x4;
typedef unsigned char u8;
typedef unsigned int u32;

#define T_SEQ   256
#define C_EMB   384
#define NH      6
#define HS      4
#define NB      128
#define NTOK    (NB * T_SEQ)   // 32768
#define VOC     65
#define FFDIM   1536
#define QKVW    72
#define PROJK   32
#define XROWS   (VOC * T_SEQ)  // 16640

#define X2_SCALE    128.0f
#define W1_SCALE    128.0f
#define FF1_DESCALE (1.0f / (128.0f * 128.0f))
#define H1_SCALE    512.0f
#define W2_SCALE    128.0f
#define FF2_DESCALE (1.0f / (512.0f * 128.0f))

__device__ __forceinline__ float bf2f(bf16 x) { return __bfloat162float(x); }
__device__ __forceinline__ bf16  f2b(float x) { return __float2bfloat16(x); }
__device__ __forceinline__ short f2s(float x) { bf16 b = __float2bfloat16(x); return *reinterpret_cast<short*>(&b); }
__device__ __forceinline__ u8 f2fp8(float x) {
    return (u8)(__builtin_amdgcn_cvt_pk_fp8_f32(x, x, 0, false) & 0xff);
}
__device__ __forceinline__ u32 pk4fp8(const float* w) {
    int p = __builtin_amdgcn_cvt_pk_fp8_f32(w[0], w[1], 0, false);
    p = __builtin_amdgcn_cvt_pk_fp8_f32(w[2], w[3], p, true);
    return (u32)p;
}

// async 16B global->LDS. LDS dst = wave-uniform base + lane*16; global addr per-lane (gather ok).
__device__ __forceinline__ void glds16(const void* g, void* l) {
    __builtin_amdgcn_global_load_lds((const __attribute__((address_space(1))) void*)g,
                                     (__attribute__((address_space(3))) void*)l, 16, 0, 0);
}

// ---------------- all weight packing + embedding table + loss-accumulator init, ONE dispatch
// W1P is FRAG-MAJOR: per (n16, k-chunk 128) a 2KB block; lane l's 32B fragment at l*32:
// n = n16*16 + (l&15), k = kchunk*128 + (l>>4)*32 + j. W2f8 is row-major [384][1536].
__global__ void pack_all_kernel(const float* __restrict__ Wq, const float* __restrict__ Wk,
                                const float* __restrict__ Wv, const float* __restrict__ Wlm,
                                const float* __restrict__ Wproj,
                                const float* __restrict__ W1, const float* __restrict__ W2,
                                const float* __restrict__ tok_emb, const float* __restrict__ pos_emb,
                                bf16* __restrict__ WqkvT, bf16* __restrict__ WlmT,
                                bf16* __restrict__ WprojT, u8* __restrict__ W1P,
                                u8* __restrict__ W2f8, bf16* __restrict__ xtab,
                                float* __restrict__ lossbuf) {
    int blk = blockIdx.x;
    int t = threadIdx.x;
    if (blk == 0 && t == 0) { lossbuf[0] = 0.f; ((int*)lossbuf)[1] = 0; }
    if (blk < 128) {                                   // WqkvT [128,384]
        int n = blk;
        for (int c = t; c < C_EMB; c += 256) {
            float v = 0.f;
            if (n < QKVW) {
                int sel = n / 24, r = n % 24, h = r >> 2, d = r & 3;
                const float* W = (sel == 0) ? Wq : (sel == 1) ? Wk : Wv;
                v = W[(h * C_EMB + c) * HS + d];
            }
            WqkvT[(size_t)n * C_EMB + c] = f2b(v);
        }
    } else if (blk < 256) {                            // WlmT [128,384]
        int n = blk - 128;
        for (int c = t; c < C_EMB; c += 256)
            WlmT[(size_t)n * C_EMB + c] = f2b(n < VOC ? Wlm[(size_t)c * VOC + n] : 0.f);
    } else if (blk < 640) {                            // WprojT [384,32]
        int n = blk - 256;
        int k = t;
        if (k < PROJK)
            WprojT[(size_t)n * PROJK + k] = f2b(k < 24 ? Wproj[(size_t)k * C_EMB + n] : 0.f);
    } else if (blk < 640 + 288) {                      // W1P frag-major: 96 n16 x 3 kk x 2KB
        int fb = blk - 640;
        int n16 = fb / 3, kk = fb % 3;
        int b0 = t * 8;                                // 8 bytes per thread
        int l = b0 >> 5;
        int j0 = b0 & 31;
        int n = n16 * 16 + (l & 15);
        int kb = kk * 128 + (l >> 4) * 32 + j0;
        union { u8 b[8]; uint2 u; } pk;
        #pragma unroll
        for (int e = 0; e < 8; ++e)
            pk.b[e] = f2fp8(W1[(size_t)(kb + e) * FFDIM + n] * W1_SCALE);
        *(uint2*)&W1P[(size_t)fb * 2048 + b0] = pk.u;
    } else if (blk < 640 + 288 + 384) {                // W2f8 [384,1536] fp8 row-major
        int n = blk - 928;
        for (int k = t; k < FFDIM; k += 256)
            W2f8[(size_t)n * FFDIM + k] = f2fp8(W2[(size_t)k * C_EMB + n] * W2_SCALE);
    } else {                                           // xtab [65*256, 384] bf16
        int base = (blk - 1312) * 4;
        for (int r = 0; r < 4; ++r) {
            int row = base + r;
            int id = row >> 8, tt = row & 255;
            const float* te = tok_emb + (size_t)id * C_EMB;
            const float* pe = pos_emb + (size_t)tt * C_EMB;
            bf16* dst = xtab + (size_t)row * C_EMB;
            for (int c = t; c < C_EMB; c += 256)
                dst[c] = f2b(te[c] + pe[c]);
        }
    }
}

// ---------------- QKV gather-GEMM, 512 threads / 8 waves, BK=64 (128B rows, (r&7)*16 rotation)
__global__ __launch_bounds__(512)
void qkv_gather_kernel(const int* __restrict__ idx, const bf16* __restrict__ xtab,
                       const bf16* __restrict__ Bt, float* __restrict__ outf) {
    __shared__ __align__(16) u8 As[16384];   // [128 rows][128B = 64 bf16], row r rotated by (r&7)*16B
    __shared__ __align__(16) u8 Bs[16384];
    __shared__ int rowid[128];
    int tid = threadIdx.x, lane = tid & 63, wave = tid >> 6;
    int bm = blockIdx.x * 128;
    int wm = (wave & 1) * 64, wn = (wave >> 1) * 32;
    int lrow = lane & 15, kq = lane >> 4;
    if (tid < 128) { int token = bm + tid; rowid[tid] = idx[token] * T_SEQ + (token & (T_SEQ - 1)); }
    __syncthreads();

    int r0 = tid >> 3;
    int s0 = (((tid & 7) * 16) - (r0 & 7) * 16) & 127;
    int c1 = tid + 512;
    int r1 = c1 >> 3;
    int s1 = (((c1 & 7) * 16) - (r1 & 7) * 16) & 127;
    const u8* xb = (const u8*)xtab;
    const u8* bb = (const u8*)Bt;
    long gA0 = (long)rowid[r0] * 768 + s0;
    long gA1 = (long)rowid[r1] * 768 + s1;
    long gB0 = (long)r0 * 768 + s0;
    long gB1 = (long)r1 * 768 + s1;
    int ro = (lrow & 7) * 16;

    f32x4 acc[4][2] = {};
    for (int k0 = 0; k0 < 768; k0 += 128) {            // k0 = byte offset within 768B row
        glds16(xb + gA0 + k0, As + (size_t)tid * 16);
        glds16(xb + gA1 + k0, As + (size_t)c1 * 16);
        glds16(bb + gB0 + k0, Bs + (size_t)tid * 16);
        glds16(bb + gB1 + k0, Bs + (size_t)c1 * 16);
        __syncthreads();
        #pragma unroll
        for (int ks = 0; ks < 2; ++ks) {
            int off = (ks * 64 + kq * 16 + ro) & 127;
            bf16x8 af[4], bff[2];
            #pragma unroll
            for (int i = 0; i < 4; ++i)
                af[i] = *(const bf16x8*)&As[(size_t)(wm + i * 16 + lrow) * 128 + off];
            #pragma unroll
            for (int i = 0; i < 2; ++i)
                bff[i] = *(const bf16x8*)&Bs[(size_t)(wn + i * 16 + lrow) * 128 + off];
            #pragma unroll
            for (int mi = 0; mi < 4; ++mi)
                #pragma unroll
                for (int ni = 0; ni < 2; ++ni)
                    acc[mi][ni] = __builtin_amdgcn_mfma_f32_16x16x32_bf16(af[mi], bff[ni], acc[mi][ni], 0, 0, 0);
        }
        __syncthreads();
    }

    #pragma unroll
    for (int ni = 0; ni < 2; ++ni) {
        int col = wn + ni * 16 + lrow;
        if (col >= QKVW) continue;
        #pragma unroll
        for (int mi = 0; mi < 4; ++mi) {
            int orow = bm + wm + mi * 16 + kq * 4;
            #pragma unroll
            for (int r = 0; r < 4; ++r)
                outf[(size_t)(orow + r) * QKVW + col] = acc[mi][ni][r];
        }
    }
}

// ---------------- causal softmax attention (no-max-stabilization form; scores << 1)
__global__ void attn_kernel(const float* __restrict__ qkv,
                            bf16* __restrict__ attnT) {
    int bh = blockIdx.x;
    int b = bh / NH, h = bh % NH;
    int t = threadIdx.x;
    __shared__ float4 kv[T_SEQ][2];    // [s][0]=k4, [s][1]=v4
    const float* base = qkv + (size_t)(b * T_SEQ) * QKVW;
    kv[t][0] = *(const float4*)(base + t * QKVW + 24 + h * HS);
    kv[t][1] = *(const float4*)(base + t * QKVW + 48 + h * HS);
    __syncthreads();
    const float scale = 0.05103103630798288f;   // 384^-0.5
    float4 q = *(const float4*)(base + t * QKVW + h * HS);
    float qx = q.x * scale, qy = q.y * scale, qz = q.z * scale, qw = q.w * scale;
    float sum0 = 0.f, sum1 = 0.f;
    float o0x = 0.f, o0y = 0.f, o0z = 0.f, o0w = 0.f;
    float o1x = 0.f, o1y = 0.f, o1z = 0.f, o1w = 0.f;
    int s = 0;
    for (; s + 1 <= t; s += 2) {
        float4 k0 = kv[s][0],     v0 = kv[s][1];
        float4 k1 = kv[s + 1][0], v1 = kv[s + 1][1];
        float p0 = __expf(qx * k0.x + qy * k0.y + qz * k0.z + qw * k0.w);
        float p1 = __expf(qx * k1.x + qy * k1.y + qz * k1.z + qw * k1.w);
        sum0 += p0; sum1 += p1;
        o0x += p0 * v0.x; o0y += p0 * v0.y; o0z += p0 * v0.z; o0w += p0 * v0.w;
        o1x += p1 * v1.x; o1y += p1 * v1.y; o1z += p1 * v1.z; o1w += p1 * v1.w;
    }
    if (s <= t) {
        float4 k0 = kv[s][0], v0 = kv[s][1];
        float p0 = __expf(qx * k0.x + qy * k0.y + qz * k0.z + qw * k0.w);
        sum0 += p0;
        o0x += p0 * v0.x; o0y += p0 * v0.y; o0z += p0 * v0.z; o0w += p0 * v0.w;
    }
    float inv = 1.f / (sum0 + sum1);
    bf16* out = attnT + (size_t)(b * T_SEQ + t) * PROJK + h * HS;
    out[0] = f2b((o0x + o1x) * inv);
    out[1] = f2b((o0y + o1y) * inv);
    out[2] = f2b((o0z + o1z) * inv);
    out[3] = f2b((o0w + o1w) * inv);
    if (h == 0) {
        bf16* pad = attnT + (size_t)(b * T_SEQ + t) * PROJK + 24;
        *(uint4*)pad = uint4{0, 0, 0, 0};
    }
}

// ---------------- proj + FF1 fused, 128-token strip, 64 KB LDS -> TRUE 2 blocks/CU.
// Proj operand fragments read DIRECTLY from L2 (no LDS staging; attnT 2MB + WprojT 24KB,
// addressing row*32 + khalf*8 == staged-rotation values). x2 in LDS (48K) + h1 chunk (16K).
// W1 frags stream coalesced frag-major global->reg (L2-hot). h1 -> HBM fp8.
__global__ __launch_bounds__(512, 4)
void ff1_kernel(const bf16* __restrict__ attnT, const bf16* __restrict__ WprojT,
                const float* __restrict__ bproj,
                const u8* __restrict__ W1P, const float* __restrict__ b1,
                u8* __restrict__ h1f8) {
    __shared__ __align__(16) u8 smem[65536];           // 64 KB exactly -> 2 blocks/CU
    u8* x2_lds = smem;                                 // [3][128][128] fp8, (m&7)*16 rotation
    u8* h1s    = smem + 49152;                         // [128][128] fp8 rotated (16 KB)

    int tid  = threadIdx.x;
    int lane = tid & 63;
    int wave = tid >> 6;
    int bm   = blockIdx.x * 128;
    int lrow  = lane & 15;
    int khalf = lane >> 4;

    // ---- proj: 2 column-phases, operands direct from L2 (frag layout = row*32 + khalf*8)
    {
        int wmP = (wave & 1) * 64;
        int wn6 = (wave >> 1) * 96;
        #pragma unroll
        for (int ph = 0; ph < 2; ++ph) {
            f32x4 accp[4][3] = {};
            bf16x8 afp[4], bfp[3];
            #pragma unroll
            for (int i = 0; i < 4; ++i)
                afp[i] = *(const bf16x8*)&attnT[(size_t)(bm + wmP + i * 16 + lrow) * PROJK + khalf * 8];
            #pragma unroll
            for (int i = 0; i < 3; ++i)
                bfp[i] = *(const bf16x8*)&WprojT[(size_t)(wn6 + (ph * 3 + i) * 16 + lrow) * PROJK + khalf * 8];
            #pragma unroll
            for (int mi = 0; mi < 4; ++mi)
                #pragma unroll
                for (int ni = 0; ni < 3; ++ni)
                    accp[mi][ni] = __builtin_amdgcn_mfma_f32_16x16x32_bf16(bfp[ni], afp[mi], accp[mi][ni], 0, 0, 0);
            // epilogue -> x2_lds (fp8 * X2_SCALE, rotated)
            #pragma unroll
            for (int mi = 0; mi < 4; ++mi) {
                int m = wmP + mi * 16 + lrow;
                #pragma unroll
                for (int ni = 0; ni < 3; ++ni) {
                    int n0 = wn6 + (ph * 3 + ni) * 16 + khalf * 4;
                    float4 bv = *(const float4*)(bproj + n0);
                    float w[4];
                    w[0] = (accp[mi][ni][0] + bv.x) * X2_SCALE;
                    w[1] = (accp[mi][ni][1] + bv.y) * X2_SCALE;
                    w[2] = (accp[mi][ni][2] + bv.z) * X2_SCALE;
                    w[3] = (accp[mi][ni][3] + bv.w) * X2_SCALE;
                    *(u32*)&x2_lds[(size_t)(n0 >> 7) * 16384 + (size_t)m * 128 +
                                   (((n0 & 127) + (m & 7) * 16) & 127)] = pk4fp8(w);
                }
            }
        }
    }
    __syncthreads();                                   // x2 ready

    // ---- FF1: 12 nt-chunks of 128 cols; wave layout 4M(32 rows) x 2N(64 cols = 4 n16)
    int wm1 = (wave & 3) * 32;
    int wc  = wave >> 2;
    int arot8 = (lrow & 7) * 16;
    int off0 = (khalf * 32 + arot8) & 127;
    int off1 = (off0 + 16) & 127;

    for (int nt = 0; nt < 12; ++nt) {
        f32x4 acc1[2][4] = {};
        #pragma unroll
        for (int kk = 0; kk < 3; ++kk) {
            const u8* abase = x2_lds + (size_t)kk * 16384;
            i32x8 a[2];
            #pragma unroll
            for (int i = 0; i < 2; ++i) {
                const u8* rp = abase + (size_t)(wm1 + i * 16 + lrow) * 128;
                i32x4 lo = *(const i32x4*)(rp + off0);
                i32x4 hi = *(const i32x4*)(rp + off1);
                a[i][0]=lo[0]; a[i][1]=lo[1]; a[i][2]=lo[2]; a[i][3]=lo[3];
                a[i][4]=hi[0]; a[i][5]=hi[1]; a[i][6]=hi[2]; a[i][7]=hi[3];
            }
            const u8* wbase = W1P + ((size_t)((nt * 8 + wc * 4) * 3 + kk)) * 2048
                                  + (size_t)lane * 32;
            #pragma unroll
            for (int j = 0; j < 4; ++j) {              // one b-frag live at a time
                const u8* p = wbase + (size_t)j * 3 * 2048;   // n16+1 advances by 3 fragblocks
                i32x4 lo = *(const i32x4*)p;
                i32x4 hi = *(const i32x4*)(p + 16);
                i32x8 b;
                b[0]=lo[0]; b[1]=lo[1]; b[2]=lo[2]; b[3]=lo[3];
                b[4]=hi[0]; b[5]=hi[1]; b[6]=hi[2]; b[7]=hi[3];
                #pragma unroll
                for (int mi = 0; mi < 2; ++mi)
                    acc1[mi][j] = __builtin_amdgcn_mfma_scale_f32_16x16x128_f8f6f4(
                        b, a[mi], acc1[mi][j], 0, 0,
                        0, 0x7f7f7f7f, 0, 0x7f7f7f7f);
            }
        }

        // ---- h1 epilogue -> h1s [128][128] (fp8 * H1_SCALE, relu, rotated)
        #pragma unroll
        for (int mi = 0; mi < 2; ++mi) {
            int m = wm1 + mi * 16 + lrow;
            #pragma unroll
            for (int ni = 0; ni < 4; ++ni) {
                int n0 = wc * 64 + ni * 16 + khalf * 4;
                float4 bv = *(const float4*)(b1 + nt * 128 + n0);
                float w[4];
                w[0] = fmaxf(acc1[mi][ni][0] * FF1_DESCALE + bv.x, 0.f) * H1_SCALE;
                w[1] = fmaxf(acc1[mi][ni][1] * FF1_DESCALE + bv.y, 0.f) * H1_SCALE;
                w[2] = fmaxf(acc1[mi][ni][2] * FF1_DESCALE + bv.z, 0.f) * H1_SCALE;
                w[3] = fmaxf(acc1[mi][ni][3] * FF1_DESCALE + bv.w, 0.f) * H1_SCALE;
                *(u32*)&h1s[(size_t)m * 128 + ((n0 + (m & 7) * 16) & 127)] = pk4fp8(w);
            }
        }
        __syncthreads();                               // h1s ready

        // ---- coalesced h1 store: 128 rows x 128B -> h1f8[bm.., nt*128..]
        #pragma unroll
        for (int p = 0; p < 2; ++p) {
            int c = tid + p * 512;
            int row = c >> 3;
            int g0 = (c & 7) * 16;
            uint4 v = *(const uint4*)&h1s[(size_t)row * 128 + ((g0 + (row & 7) * 16) & 127)];
            *(uint4*)&h1f8[(size_t)(bm + row) * FFDIM + nt * 128 + g0] = v;
        }
        __syncthreads();                               // h1s free for next nt
    }
}

// ---------------- unified fp8 MX-scaled MFMA GEMM (round-0-proven form), BK=128, 512 threads,
// bank-swizzled, XCD-aware block swizzle; SWAPPED operands + LDS-staged coalesced epilogue.
__global__ __launch_bounds__(512)
void gemm_fp8_kernel(const u8* __restrict__ A, const u8* __restrict__ Bt,
                     const float* __restrict__ bias,
                     bf16* __restrict__ outb, u8* __restrict__ outf8,
                     float descale, float oscale,
                     int M, int K, int Nout, int NT, int relu) {
    __shared__ u8 smem[32768];
    u8* As = smem;            // [128][128], rows rotated by (r&7)*16B
    u8* Bs = smem + 16384;
    int lin  = blockIdx.x;
    int xcd  = lin & 7;
    int loc  = lin >> 3;
    int nt   = loc % NT;
    int mloc = loc / NT;
    int MPX  = (M / 128) >> 3;
    int bm = (xcd * MPX + mloc) * 128;
    int bn = nt * 128;

    int tid  = threadIdx.x;
    int lane = tid & 63;
    int wave = tid >> 6;
    int wm = (wave & 1) * 64;
    int wn = (wave >> 1) * 32;
    int lrow  = lane & 15;
    int khalf = lane >> 4;

    f32x4 acc[4][2] = {};
    int r0 = tid >> 3;
    int i0 = (tid & 7) * 16;
    int s0 = (i0 - (r0 & 7) * 16) & 127;
    int arot = (lrow & 7) * 16;
    int off0 = (khalf * 32 + arot) & 127;
    int off1 = (off0 + 16) & 127;

    for (int k0 = 0; k0 < K; k0 += 128) {
        const u8* Ag = A  + (size_t)(bm + r0) * K + k0 + s0;
        const u8* Bg = Bt + (size_t)(bn + r0) * K + k0 + s0;
        glds16(Ag,                  As + (size_t)tid * 16);
        glds16(Ag + (size_t)64 * K, As + 8192 + (size_t)tid * 16);
        glds16(Bg,                  Bs + (size_t)tid * 16);
        glds16(Bg + (size_t)64 * K, Bs + 8192 + (size_t)tid * 16);
        __syncthreads();

        i32x8 a[4], b[2];
        #pragma unroll
        for (int i = 0; i < 4; ++i) {
            const u8* rp = As + (size_t)(wm + i * 16 + lrow) * 128;
            i32x4 lo = *(const i32x4*)(rp + off0);
            i32x4 hi = *(const i32x4*)(rp + off1);
            a[i][0]=lo[0]; a[i][1]=lo[1]; a[i][2]=lo[2]; a[i][3]=lo[3];
            a[i][4]=hi[0]; a[i][5]=hi[1]; a[i][6]=hi[2]; a[i][7]=hi[3];
        }
        #pragma unroll
        for (int i = 0; i < 2; ++i) {
            const u8* rp = Bs + (size_t)(wn + i * 16 + lrow) * 128;
            i32x4 lo = *(const i32x4*)(rp + off0);
            i32x4 hi = *(const i32x4*)(rp + off1);
            b[i][0]=lo[0]; b[i][1]=lo[1]; b[i][2]=lo[2]; b[i][3]=lo[3];
            b[i][4]=hi[0]; b[i][5]=hi[1]; b[i][6]=hi[2]; b[i][7]=hi[3];
        }
        // swapped: lane holds 4 consecutive n at fixed m
        #pragma unroll
        for (int mi = 0; mi < 4; ++mi)
            #pragma unroll
            for (int ni = 0; ni < 2; ++ni)
                acc[mi][ni] = __builtin_amdgcn_mfma_scale_f32_16x16x128_f8f6f4(
                    b[ni], a[mi], acc[mi][ni], 0, 0,
                    0, 0x7f7f7f7f, 0, 0x7f7f7f7f);
        __syncthreads();
    }

    // staged epilogue: pack per-lane 4n values -> LDS (rotated), then coalesced stores
    if (outf8) {
        #pragma unroll
        for (int mi = 0; mi < 4; ++mi) {
            int m = wm + mi * 16 + lrow;
            #pragma unroll
            for (int ni = 0; ni < 2; ++ni) {
                int n0 = wn + ni * 16 + khalf * 4;
                float4 bv = *(const float4*)(bias + bn + n0);
                float w[4];
                w[0] = acc[mi][ni][0] * descale + bv.x;
                w[1] = acc[mi][ni][1] * descale + bv.y;
                w[2] = acc[mi][ni][2] * descale + bv.z;
                w[3] = acc[mi][ni][3] * descale + bv.w;
                if (relu) {
                    w[0] = fmaxf(w[0], 0.f); w[1] = fmaxf(w[1], 0.f);
                    w[2] = fmaxf(w[2], 0.f); w[3] = fmaxf(w[3], 0.f);
                }
                w[0] *= oscale; w[1] *= oscale; w[2] *= oscale; w[3] *= oscale;
                *(u32*)&smem[(size_t)m * 128 + ((n0 + (m & 7) * 16) & 127)] = pk4fp8(w);
            }
        }
        __syncthreads();
        #pragma unroll
        for (int p = 0; p < 2; ++p) {
            int c = tid + p * 512;
            int row = c >> 3;
            int g0 = (c & 7) * 16;
            uint4 v = *(const uint4*)&smem[(size_t)row * 128 + ((g0 + (row & 7) * 16) & 127)];
            *(uint4*)&outf8[(size_t)(bm + row) * Nout + bn + g0] = v;
        }
    } else {
        short* Es = (short*)smem;   // [128][128] shorts = 32 KB, rows rotated by (r&7)*16B
        #pragma unroll
        for (int mi = 0; mi < 4; ++mi) {
            int m = wm + mi * 16 + lrow;
            #pragma unroll
            for (int ni = 0; ni < 2; ++ni) {
                int n0 = wn + ni * 16 + khalf * 4;
                float4 bv = *(const float4*)(bias + bn + n0);
                union { short s[4]; uint2 u; } pk;
                pk.s[0] = f2s(acc[mi][ni][0] * descale + bv.x);
                pk.s[1] = f2s(acc[mi][ni][1] * descale + bv.y);
                pk.s[2] = f2s(acc[mi][ni][2] * descale + bv.z);
                pk.s[3] = f2s(acc[mi][ni][3] * descale + bv.w);
                *(uint2*)&Es[(size_t)m * 128 + ((n0 + (m & 7) * 8) & 127)] = pk.u;
            }
        }
        __syncthreads();
        #pragma unroll
        for (int p = 0; p < 4; ++p) {
            int c = tid + p * 512;
            int row = c >> 4;
            int g0 = (c & 15) * 16;   // byte offset in 256B row
            uint4 v = *(const uint4*)&smem[(size_t)row * 256 + ((g0 + (row & 7) * 16) & 255)];
            *(uint4*)((u8*)outb + ((size_t)(bm + row) * Nout + bn) * 2 + g0) = v;
        }
    }
}

// ---------------- LM head (qkv-proven BK=64 skeleton) + fused CE loss + grid loss finish
__global__ __launch_bounds__(512)
void lm_loss_kernel(const bf16* __restrict__ A, const bf16* __restrict__ Bt,
                    const float* __restrict__ bias, const int* __restrict__ targets,
                    float* __restrict__ outf, float* __restrict__ lossbuf,
                    float* __restrict__ out_loss) {
    __shared__ __align__(16) u8 As[16384];   // [128 rows][128B], row r rotated by (r&7)*16B
    __shared__ __align__(16) u8 Bs[16384];
    __shared__ float Ls[128][66];
    __shared__ float red[128];
    int tid  = threadIdx.x;
    int lane = tid & 63;
    int wave = tid >> 6;
    int bm = blockIdx.x * 128;
    int wm = (wave & 1) * 64;
    int wn = (wave >> 1) * 32;
    int lrow  = lane & 15;
    int khalf = lane >> 4;

    int r0 = tid >> 3;
    int s0 = (((tid & 7) * 16) - (r0 & 7) * 16) & 127;
    int c1 = tid + 512;
    int r1 = c1 >> 3;
    int s1 = (((c1 & 7) * 16) - (r1 & 7) * 16) & 127;
    const u8* ab = (const u8*)A;
    const u8* bb = (const u8*)Bt;
    long gA0 = (long)(bm + r0) * 768 + s0;
    long gA1 = (long)(bm + r1) * 768 + s1;
    long gB0 = (long)r0 * 768 + s0;
    long gB1 = (long)r1 * 768 + s1;
    int ro = (lrow & 7) * 16;

    f32x4 acc[4][2] = {};
    for (int k0 = 0; k0 < 768; k0 += 128) {            // k0 = byte offset within 768B row
        glds16(ab + gA0 + k0, As + (size_t)tid * 16);
        glds16(ab + gA1 + k0, As + (size_t)c1 * 16);
        glds16(bb + gB0 + k0, Bs + (size_t)tid * 16);
        glds16(bb + gB1 + k0, Bs + (size_t)c1 * 16);
        __syncthreads();
        #pragma unroll
        for (int ks = 0; ks < 2; ++ks) {
            int off = (ks * 64 + khalf * 16 + ro) & 127;
            bf16x8 af[4], bff[2];
            #pragma unroll
            for (int i = 0; i < 4; ++i)
                af[i] = *(const bf16x8*)&As[(size_t)(wm + i * 16 + lrow) * 128 + off];
            #pragma unroll
            for (int i = 0; i < 2; ++i)
                bff[i] = *(const bf16x8*)&Bs[(size_t)(wn + i * 16 + lrow) * 128 + off];
            #pragma unroll
            for (int mi = 0; mi < 4; ++mi)
                #pragma unroll
                for (int ni = 0; ni < 2; ++ni)
                    acc[mi][ni] = __builtin_amdgcn_mfma_f32_16x16x32_bf16(af[mi], bff[ni], acc[mi][ni], 0, 0, 0);
        }
        __syncthreads();
    }

    #pragma unroll
    for (int ni = 0; ni < 2; ++ni) {
        int col = wn + ni * 16 + lrow;
        if (col >= VOC) continue;
        float bv = bias[col];
        #pragma unroll
        for (int mi = 0; mi < 4; ++mi) {
            int lr = wm + mi * 16 + khalf * 4;
            #pragma unroll
            for (int r = 0; r < 4; ++r) {
                float v = acc[mi][ni][r] + bv;
                outf[(size_t)(bm + lr + r) * VOC + col] = v;
                Ls[lr + r][col] = v;
            }
        }
    }
    __syncthreads();

    if (tid < 128) {
        int token = bm + tid;
        int tgt = targets[token];
        float m = -1e30f, s = 0.f;
        #pragma unroll 8
        for (int c = 0; c < VOC; ++c) {
            float v = Ls[tid][c];
            float mn = fmaxf(m, v);
            s = s * __expf(m - mn) + __expf(v - mn);
            m = mn;
        }
        red[tid] = m + logf(s) - Ls[tid][tgt];
    }
    __syncthreads();
    if (tid < 64) {
        float s = red[tid] + red[tid + 64];
        #pragma unroll
        for (int off = 32; off > 0; off >>= 1) s += __shfl_xor(s, off);
        if (tid == 0) {
            atomicAdd(&lossbuf[0], s);
            __threadfence();
            int done = atomicAdd(&((int*)lossbuf)[1], 1);
            if (done == (NTOK / 128) - 1) {     // last block
                __threadfence();
                float total = atomicAdd(&lossbuf[0], 0.0f);
                out_loss[0] = total / (float)NTOK;
            }
        }
    }
}

extern "C" void kernel_launch(void* const* d_in, const int* in_sizes, int n_in,
                              void* d_out, int out_size, void* d_ws, size_t ws_size,
                              hipStream_t stream) {
    const int*   idx     = (const int*)  d_in[0];
    const int*   targets = (const int*)  d_in[1];
    const float* tok_emb = (const float*)d_in[2];
    const float* pos_emb = (const float*)d_in[3];
    const float* Wq      = (const float*)d_in[4];
    const float* Wk      = (const float*)d_in[5];
    const float* Wv      = (const float*)d_in[6];
    const float* Wproj   = (const float*)d_in[7];
    const float* bproj   = (const float*)d_in[8];
    const float* W1      = (const float*)d_in[9];
    const float* b1      = (const float*)d_in[10];
    const float* W2      = (const float*)d_in[11];
    const float* b2      = (const float*)d_in[12];
    const float* Wlm     = (const float*)d_in[13];
    const float* blm     = (const float*)d_in[14];

    char* ws = (char*)d_ws;
    bf16*  WprojT = (bf16*) (ws + 0);                       // 24576 B
    float* qkvbuf = (float*)(ws + 25165824);                // 9437184 B
    bf16*  attnT  = (bf16*) (ws + 34603008);                // 2097152 B
    bf16*  xtab   = (bf16*) (ws + 37748736);                // 12779520 B
    u8*    h1f8   = (u8*)   (ws + 62914560);                // 50331648 B
    bf16*  x3     = (bf16*) (ws + 163577856);               // 25165824 B
    float* lossbuf= (float*)(ws + 188743680);               // [0]=sum, [1]=counter
    u8*    W1P    = (u8*)   (ws + 188874752);               // 589824 B (frag-major)
    u8*    W2f8   = (u8*)   (ws + 190054400);               // 589824 B (row-major)
    bf16*  WqkvT  = (bf16*) (ws + 191234048);               // 98304 B
    bf16*  WlmT   = (bf16*) (ws + 191332352);               // 98304 B

    float* out_logits = (float*)d_out;                      // [32768*65] f32
    float* out_loss   = out_logits + (size_t)NTOK * VOC;    // [1]

    pack_all_kernel<<<1312 + XROWS / 4, 256, 0, stream>>>(
        Wq, Wk, Wv, Wlm, Wproj, W1, W2, tok_emb, pos_emb,
        WqkvT, WlmT, WprojT, W1P, W2f8, xtab, lossbuf);

    qkv_gather_kernel<<<NTOK / 128, 512, 0, stream>>>(idx, xtab, WqkvT, qkvbuf);
    attn_kernel<<<NB * NH, T_SEQ, 0, stream>>>(qkvbuf, attnT);

    // proj + FF1 fused: attnT -> h1f8 (x2 in LDS; W1 streams from L2), 64KB -> 2 blocks/CU
    ff1_kernel<<<NTOK / 128, 512, 0, stream>>>(attnT, WprojT, bproj, W1P, b1, h1f8);

    // FF2: fp8 [32768,1536] @ fp8 [1536->384] + b2 -> x3 bf16. NT=3. (round-0-proven kernel)
    gemm_fp8_kernel<<<(NTOK / 128) * (C_EMB / 128), 512, 0, stream>>>(h1f8, W2f8, b2,
                                                                      x3, nullptr,
                                                                      FF2_DESCALE, 1.0f,
                                                                      NTOK, FFDIM, C_EMB, C_EMB / 128, 0);

    // LM head + fused loss + grid loss finish
    lm_loss_kernel<<<NTOK / 128, 512, 0, stream>>>(x3, WlmT, blm, targets,
                                                   out_logits, lossbuf, out_loss);
}

// Round 9
// 220.141 us; speedup vs baseline: 1.0882x; 1.0882x over previous
//
#include <hip/hip_runtime.h>
#include <hip/hip_bf16.h>
#include <math.h>

typedef __hip_bfloat16 bf16;
typedef __attribute__((ext_vector_type(8))) short bf16x8;
typedef __attribute__((ext_vector_type(4))) float f32x4;
typedef __attribute__((ext_vector_type(8))) int i32x8;
typedef __attribute__((ext_vector_type(4))) int i32x4;
typedef unsigned char u8;
typedef unsigned int u32;

#define T_SEQ   256
#define C_EMB   384
#define NH      6
#define HS      4
#define NB      128
#define NTOK    (NB * T_SEQ)   // 32768
#define VOC     65
#define FFDIM   1536
#define QKVW    72
#define PROJK   32
#define XROWS   (VOC * T_SEQ)  // 16640

#define X2_SCALE    128.0f
#define W1_SCALE    128.0f
#define FF1_DESCALE (1.0f / (128.0f * 128.0f))
#define H1_SCALE    512.0f
#define W2_SCALE    128.0f
#define FF2_DESCALE (1.0f / (512.0f * 128.0f))

__device__ __forceinline__ float bf2f(bf16 x) { return __bfloat162float(x); }
__device__ __forceinline__ bf16  f2b(float x) { return __float2bfloat16(x); }
__device__ __forceinline__ short f2s(float x) { bf16 b = __float2bfloat16(x); return *reinterpret_cast<short*>(&b); }
__device__ __forceinline__ u8 f2fp8(float x) {
    return (u8)(__builtin_amdgcn_cvt_pk_fp8_f32(x, x, 0, false) & 0xff);
}
__device__ __forceinline__ u32 pk4fp8(const float* w) {
    int p = __builtin_amdgcn_cvt_pk_fp8_f32(w[0], w[1], 0, false);
    p = __builtin_amdgcn_cvt_pk_fp8_f32(w[2], w[3], p, true);
    return (u32)p;
}

// async 16B global->LDS. LDS dst = wave-uniform base + lane*16; global addr per-lane (gather ok).
__device__ __forceinline__ void glds16(const void* g, void* l) {
    __builtin_amdgcn_global_load_lds((const __attribute__((address_space(1))) void*)g,
                                     (__attribute__((address_space(3))) void*)l, 16, 0, 0);
}

// ---------------- all weight packing + embedding table + loss-accumulator init, ONE dispatch
// W1P is FRAG-MAJOR: per (n16, k-chunk 128) a 2KB block; lane l's 32B fragment at l*32:
// n = n16*16 + (l&15), k = kchunk*128 + (l>>4)*32 + j. W2f8 is row-major [384][1536].
__global__ void pack_all_kernel(const float* __restrict__ Wq, const float* __restrict__ Wk,
                                const float* __restrict__ Wv, const float* __restrict__ Wlm,
                                const float* __restrict__ Wproj,
                                const float* __restrict__ W1, const float* __restrict__ W2,
                                const float* __restrict__ tok_emb, const float* __restrict__ pos_emb,
                                bf16* __restrict__ WqkvT, bf16* __restrict__ WlmT,
                                bf16* __restrict__ WprojT, u8* __restrict__ W1P,
                                u8* __restrict__ W2f8, bf16* __restrict__ xtab,
                                float* __restrict__ lossbuf) {
    int blk = blockIdx.x;
    int t = threadIdx.x;
    if (blk == 0 && t == 0) { lossbuf[0] = 0.f; ((int*)lossbuf)[1] = 0; }
    if (blk < 128) {                                   // WqkvT [128,384]
        int n = blk;
        for (int c = t; c < C_EMB; c += 256) {
            float v = 0.f;
            if (n < QKVW) {
                int sel = n / 24, r = n % 24, h = r >> 2, d = r & 3;
                const float* W = (sel == 0) ? Wq : (sel == 1) ? Wk : Wv;
                v = W[(h * C_EMB + c) * HS + d];
            }
            WqkvT[(size_t)n * C_EMB + c] = f2b(v);
        }
    } else if (blk < 256) {                            // WlmT [128,384]
        int n = blk - 128;
        for (int c = t; c < C_EMB; c += 256)
            WlmT[(size_t)n * C_EMB + c] = f2b(n < VOC ? Wlm[(size_t)c * VOC + n] : 0.f);
    } else if (blk < 640) {                            // WprojT [384,32]
        int n = blk - 256;
        int k = t;
        if (k < PROJK)
            WprojT[(size_t)n * PROJK + k] = f2b(k < 24 ? Wproj[(size_t)k * C_EMB + n] : 0.f);
    } else if (blk < 640 + 288) {                      // W1P frag-major: 96 n16 x 3 kk x 2KB
        int fb = blk - 640;
        int n16 = fb / 3, kk = fb % 3;
        int b0 = t * 8;                                // 8 bytes per thread
        int l = b0 >> 5;
        int j0 = b0 & 31;
        int n = n16 * 16 + (l & 15);
        int kb = kk * 128 + (l >> 4) * 32 + j0;
        union { u8 b[8]; uint2 u; } pk;
        #pragma unroll
        for (int e = 0; e < 8; ++e)
            pk.b[e] = f2fp8(W1[(size_t)(kb + e) * FFDIM + n] * W1_SCALE);
        *(uint2*)&W1P[(size_t)fb * 2048 + b0] = pk.u;
    } else if (blk < 640 + 288 + 384) {                // W2f8 [384,1536] fp8 row-major
        int n = blk - 928;
        for (int k = t; k < FFDIM; k += 256)
            W2f8[(size_t)n * FFDIM + k] = f2fp8(W2[(size_t)k * C_EMB + n] * W2_SCALE);
    } else {                                           // xtab [65*256, 384] bf16
        int base = (blk - 1312) * 4;
        for (int r = 0; r < 4; ++r) {
            int row = base + r;
            int id = row >> 8, tt = row & 255;
            const float* te = tok_emb + (size_t)id * C_EMB;
            const float* pe = pos_emb + (size_t)tt * C_EMB;
            bf16* dst = xtab + (size_t)row * C_EMB;
            for (int c = t; c < C_EMB; c += 256)
                dst[c] = f2b(te[c] + pe[c]);
        }
    }
}

// ---------------- QKV gather-GEMM, 64-token strips (grid 512 -> 2 blocks/CU co-residency),
// 512 threads / 8 waves, BK=64 (128B rows, (r&7)*16 rotation)
__global__ __launch_bounds__(512)
void qkv_gather_kernel(const int* __restrict__ idx, const bf16* __restrict__ xtab,
                       const bf16* __restrict__ Bt, float* __restrict__ outf) {
    __shared__ __align__(16) u8 As[8192];    // [64 rows][128B], row r rotated by (r&7)*16B
    __shared__ __align__(16) u8 Bs[16384];   // [128 rows][128B]
    __shared__ int rowid[64];
    int tid = threadIdx.x, lane = tid & 63, wave = tid >> 6;
    int bm = blockIdx.x * 64;
    int wm = (wave & 1) * 32, wn = (wave >> 1) * 32;
    int lrow = lane & 15, kq = lane >> 4;
    if (tid < 64) { int token = bm + tid; rowid[tid] = idx[token] * T_SEQ + (token & (T_SEQ - 1)); }
    __syncthreads();

    int r0 = tid >> 3;                                 // 0..63 (A rows)
    int s0 = (((tid & 7) * 16) - (r0 & 7) * 16) & 127;
    int c1 = tid + 512;
    int r1 = c1 >> 3;                                  // B rows 64..127
    int s1 = (((c1 & 7) * 16) - (r1 & 7) * 16) & 127;
    const u8* xb = (const u8*)xtab;
    const u8* bb = (const u8*)Bt;
    long gA0 = (long)rowid[r0] * 768 + s0;
    long gB0 = (long)r0 * 768 + s0;
    long gB1 = (long)r1 * 768 + s1;
    int ro = (lrow & 7) * 16;

    f32x4 acc[2][2] = {};
    for (int k0 = 0; k0 < 768; k0 += 128) {            // k0 = byte offset within 768B row
        glds16(xb + gA0 + k0, As + (size_t)tid * 16);
        glds16(bb + gB0 + k0, Bs + (size_t)tid * 16);
        glds16(bb + gB1 + k0, Bs + (size_t)c1 * 16);
        __syncthreads();
        #pragma unroll
        for (int ks = 0; ks < 2; ++ks) {
            int off = (ks * 64 + kq * 16 + ro) & 127;
            bf16x8 af[2], bff[2];
            #pragma unroll
            for (int i = 0; i < 2; ++i)
                af[i] = *(const bf16x8*)&As[(size_t)(wm + i * 16 + lrow) * 128 + off];
            #pragma unroll
            for (int i = 0; i < 2; ++i)
                bff[i] = *(const bf16x8*)&Bs[(size_t)(wn + i * 16 + lrow) * 128 + off];
            #pragma unroll
            for (int mi = 0; mi < 2; ++mi)
                #pragma unroll
                for (int ni = 0; ni < 2; ++ni)
                    acc[mi][ni] = __builtin_amdgcn_mfma_f32_16x16x32_bf16(af[mi], bff[ni], acc[mi][ni], 0, 0, 0);
        }
        __syncthreads();
    }

    #pragma unroll
    for (int ni = 0; ni < 2; ++ni) {
        int col = wn + ni * 16 + lrow;
        if (col >= QKVW) continue;
        #pragma unroll
        for (int mi = 0; mi < 2; ++mi) {
            int orow = bm + wm + mi * 16 + kq * 4;
            #pragma unroll
            for (int r = 0; r < 2; ++r) {
                // note: 4 rows per khalf quadrant as before
            }
            #pragma unroll
            for (int r = 0; r < 4; ++r)
                outf[(size_t)(orow + r) * QKVW + col] = acc[mi][ni][r];
        }
    }
}

// ---------------- causal softmax attention (no-max-stabilization form; scores << 1)
__global__ void attn_kernel(const float* __restrict__ qkv,
                            bf16* __restrict__ attnT) {
    int bh = blockIdx.x;
    int b = bh / NH, h = bh % NH;
    int t = threadIdx.x;
    __shared__ float4 kv[T_SEQ][2];    // [s][0]=k4, [s][1]=v4
    const float* base = qkv + (size_t)(b * T_SEQ) * QKVW;
    kv[t][0] = *(const float4*)(base + t * QKVW + 24 + h * HS);
    kv[t][1] = *(const float4*)(base + t * QKVW + 48 + h * HS);
    __syncthreads();
    const float scale = 0.05103103630798288f;   // 384^-0.5
    float4 q = *(const float4*)(base + t * QKVW + h * HS);
    float qx = q.x * scale, qy = q.y * scale, qz = q.z * scale, qw = q.w * scale;
    float sum0 = 0.f, sum1 = 0.f;
    float o0x = 0.f, o0y = 0.f, o0z = 0.f, o0w = 0.f;
    float o1x = 0.f, o1y = 0.f, o1z = 0.f, o1w = 0.f;
    int s = 0;
    for (; s + 1 <= t; s += 2) {
        float4 k0 = kv[s][0],     v0 = kv[s][1];
        float4 k1 = kv[s + 1][0], v1 = kv[s + 1][1];
        float p0 = __expf(qx * k0.x + qy * k0.y + qz * k0.z + qw * k0.w);
        float p1 = __expf(qx * k1.x + qy * k1.y + qz * k1.z + qw * k1.w);
        sum0 += p0; sum1 += p1;
        o0x += p0 * v0.x; o0y += p0 * v0.y; o0z += p0 * v0.z; o0w += p0 * v0.w;
        o1x += p1 * v1.x; o1y += p1 * v1.y; o1z += p1 * v1.z; o1w += p1 * v1.w;
    }
    if (s <= t) {
        float4 k0 = kv[s][0], v0 = kv[s][1];
        float p0 = __expf(qx * k0.x + qy * k0.y + qz * k0.z + qw * k0.w);
        sum0 += p0;
        o0x += p0 * v0.x; o0y += p0 * v0.y; o0z += p0 * v0.z; o0w += p0 * v0.w;
    }
    float inv = 1.f / (sum0 + sum1);
    bf16* out = attnT + (size_t)(b * T_SEQ + t) * PROJK + h * HS;
    out[0] = f2b((o0x + o1x) * inv);
    out[1] = f2b((o0y + o1y) * inv);
    out[2] = f2b((o0z + o1z) * inv);
    out[3] = f2b((o0w + o1w) * inv);
    if (h == 0) {
        bf16* pad = attnT + (size_t)(b * T_SEQ + t) * PROJK + 24;
        *(uint4*)pad = uint4{0, 0, 0, 0};
    }
}

// ---------------- proj + FF1 fused, 64-token strip (grid 512 -> 2 blocks/CU), 40 KB LDS.
// Proj operand fragments direct from L2; x2 [3][64][128] in LDS; W1 frags stream coalesced
// frag-major global->reg (L2-hot); h1 -> HBM fp8 via rotated-LDS coalesced stores.
__global__ __launch_bounds__(512, 4)
void ff1_kernel(const bf16* __restrict__ attnT, const bf16* __restrict__ WprojT,
                const float* __restrict__ bproj,
                const u8* __restrict__ W1P, const float* __restrict__ b1,
                u8* __restrict__ h1f8) {
    __shared__ __align__(16) u8 smem[40960];           // 40 KB -> 2+ blocks/CU by LDS
    u8* x2_lds = smem;                                 // [3][64][128] fp8, (m&7)*16 rotation
    u8* h1s    = smem + 24576;                         // [64][256] fp8 rotated (16 KB)

    int tid  = threadIdx.x;
    int lane = tid & 63;
    int wave = tid >> 6;
    int bm   = blockIdx.x * 64;
    int lrow  = lane & 15;
    int khalf = lane >> 4;

    // ---- proj: 2 column-phases, operands direct from L2 (frag layout = row*32 + khalf*8)
    {
        int wmP = (wave & 1) * 32;
        int wn6 = (wave >> 1) * 96;
        #pragma unroll
        for (int ph = 0; ph < 2; ++ph) {
            f32x4 accp[2][3] = {};
            bf16x8 afp[2], bfp[3];
            #pragma unroll
            for (int i = 0; i < 2; ++i)
                afp[i] = *(const bf16x8*)&attnT[(size_t)(bm + wmP + i * 16 + lrow) * PROJK + khalf * 8];
            #pragma unroll
            for (int i = 0; i < 3; ++i)
                bfp[i] = *(const bf16x8*)&WprojT[(size_t)(wn6 + (ph * 3 + i) * 16 + lrow) * PROJK + khalf * 8];
            #pragma unroll
            for (int mi = 0; mi < 2; ++mi)
                #pragma unroll
                for (int ni = 0; ni < 3; ++ni)
                    accp[mi][ni] = __builtin_amdgcn_mfma_f32_16x16x32_bf16(bfp[ni], afp[mi], accp[mi][ni], 0, 0, 0);
            // epilogue -> x2_lds (fp8 * X2_SCALE, rotated)
            #pragma unroll
            for (int mi = 0; mi < 2; ++mi) {
                int m = wmP + mi * 16 + lrow;
                #pragma unroll
                for (int ni = 0; ni < 3; ++ni) {
                    int n0 = wn6 + (ph * 3 + ni) * 16 + khalf * 4;
                    float4 bv = *(const float4*)(bproj + n0);
                    float w[4];
                    w[0] = (accp[mi][ni][0] + bv.x) * X2_SCALE;
                    w[1] = (accp[mi][ni][1] + bv.y) * X2_SCALE;
                    w[2] = (accp[mi][ni][2] + bv.z) * X2_SCALE;
                    w[3] = (accp[mi][ni][3] + bv.w) * X2_SCALE;
                    *(u32*)&x2_lds[(size_t)(n0 >> 7) * 8192 + (size_t)m * 128 +
                                   (((n0 & 127) + (m & 7) * 16) & 127)] = pk4fp8(w);
                }
            }
        }
    }
    __syncthreads();                                   // x2 ready

    // ---- FF1: 6 nt-chunks of 256 cols; wave layout 2M(32 rows) x 4N(64 cols = 4 n16)
    int wm1 = (wave & 1) * 32;
    int wc  = wave >> 1;
    int arot8 = (lrow & 7) * 16;
    int off0 = (khalf * 32 + arot8) & 127;
    int off1 = (off0 + 16) & 127;

    for (int nt = 0; nt < 6; ++nt) {
        f32x4 acc1[2][4] = {};
        #pragma unroll
        for (int kk = 0; kk < 3; ++kk) {
            const u8* abase = x2_lds + (size_t)kk * 8192;
            i32x8 a[2];
            #pragma unroll
            for (int i = 0; i < 2; ++i) {
                const u8* rp = abase + (size_t)(wm1 + i * 16 + lrow) * 128;
                i32x4 lo = *(const i32x4*)(rp + off0);
                i32x4 hi = *(const i32x4*)(rp + off1);
                a[i][0]=lo[0]; a[i][1]=lo[1]; a[i][2]=lo[2]; a[i][3]=lo[3];
                a[i][4]=hi[0]; a[i][5]=hi[1]; a[i][6]=hi[2]; a[i][7]=hi[3];
            }
            const u8* wbase = W1P + ((size_t)((nt * 16 + wc * 4) * 3 + kk)) * 2048
                                  + (size_t)lane * 32;
            #pragma unroll
            for (int j = 0; j < 4; ++j) {              // one b-frag live at a time
                const u8* p = wbase + (size_t)j * 3 * 2048;   // n16+1 advances by 3 fragblocks
                i32x4 lo = *(const i32x4*)p;
                i32x4 hi = *(const i32x4*)(p + 16);
                i32x8 b;
                b[0]=lo[0]; b[1]=lo[1]; b[2]=lo[2]; b[3]=lo[3];
                b[4]=hi[0]; b[5]=hi[1]; b[6]=hi[2]; b[7]=hi[3];
                #pragma unroll
                for (int mi = 0; mi < 2; ++mi)
                    acc1[mi][j] = __builtin_amdgcn_mfma_scale_f32_16x16x128_f8f6f4(
                        b, a[mi], acc1[mi][j], 0, 0,
                        0, 0x7f7f7f7f, 0, 0x7f7f7f7f);
            }
        }

        // ---- h1 epilogue -> h1s [64][256] (fp8 * H1_SCALE, relu, rotated mod 256)
        #pragma unroll
        for (int mi = 0; mi < 2; ++mi) {
            int m = wm1 + mi * 16 + lrow;
            #pragma unroll
            for (int ni = 0; ni < 4; ++ni) {
                int n0 = wc * 64 + ni * 16 + khalf * 4;
                float4 bv = *(const float4*)(b1 + nt * 256 + n0);
                float w[4];
                w[0] = fmaxf(acc1[mi][ni][0] * FF1_DESCALE + bv.x, 0.f) * H1_SCALE;
                w[1] = fmaxf(acc1[mi][ni][1] * FF1_DESCALE + bv.y, 0.f) * H1_SCALE;
                w[2] = fmaxf(acc1[mi][ni][2] * FF1_DESCALE + bv.z, 0.f) * H1_SCALE;
                w[3] = fmaxf(acc1[mi][ni][3] * FF1_DESCALE + bv.w, 0.f) * H1_SCALE;
                *(u32*)&h1s[(size_t)m * 256 + ((n0 + (m & 7) * 16) & 255)] = pk4fp8(w);
            }
        }
        __syncthreads();                               // h1s ready

        // ---- coalesced h1 store: 64 rows x 256B -> h1f8[bm.., nt*256..]
        #pragma unroll
        for (int p = 0; p < 2; ++p) {
            int c = tid + p * 512;
            int row = c >> 4;
            int g0 = (c & 15) * 16;
            uint4 v = *(const uint4*)&h1s[(size_t)row * 256 + ((g0 + (row & 7) * 16) & 255)];
            *(uint4*)&h1f8[(size_t)(bm + row) * FFDIM + nt * 256 + g0] = v;
        }
        __syncthreads();                               // h1s free for next nt
    }
}

// ---------------- unified fp8 MX-scaled MFMA GEMM (round-0-proven form), BK=128, 512 threads,
// bank-swizzled, XCD-aware block swizzle; SWAPPED operands + LDS-staged coalesced epilogue.
__global__ __launch_bounds__(512)
void gemm_fp8_kernel(const u8* __restrict__ A, const u8* __restrict__ Bt,
                     const float* __restrict__ bias,
                     bf16* __restrict__ outb, u8* __restrict__ outf8,
                     float descale, float oscale,
                     int M, int K, int Nout, int NT, int relu) {
    __shared__ u8 smem[32768];
    u8* As = smem;            // [128][128], rows rotated by (r&7)*16B
    u8* Bs = smem + 16384;
    int lin  = blockIdx.x;
    int xcd  = lin & 7;
    int loc  = lin >> 3;
    int nt   = loc % NT;
    int mloc = loc / NT;
    int MPX  = (M / 128) >> 3;
    int bm = (xcd * MPX + mloc) * 128;
    int bn = nt * 128;

    int tid  = threadIdx.x;
    int lane = tid & 63;
    int wave = tid >> 6;
    int wm = (wave & 1) * 64;
    int wn = (wave >> 1) * 32;
    int lrow  = lane & 15;
    int khalf = lane >> 4;

    f32x4 acc[4][2] = {};
    int r0 = tid >> 3;
    int i0 = (tid & 7) * 16;
    int s0 = (i0 - (r0 & 7) * 16) & 127;
    int arot = (lrow & 7) * 16;
    int off0 = (khalf * 32 + arot) & 127;
    int off1 = (off0 + 16) & 127;

    for (int k0 = 0; k0 < K; k0 += 128) {
        const u8* Ag = A  + (size_t)(bm + r0) * K + k0 + s0;
        const u8* Bg = Bt + (size_t)(bn + r0) * K + k0 + s0;
        glds16(Ag,                  As + (size_t)tid * 16);
        glds16(Ag + (size_t)64 * K, As + 8192 + (size_t)tid * 16);
        glds16(Bg,                  Bs + (size_t)tid * 16);
        glds16(Bg + (size_t)64 * K, Bs + 8192 + (size_t)tid * 16);
        __syncthreads();

        i32x8 a[4], b[2];
        #pragma unroll
        for (int i = 0; i < 4; ++i) {
            const u8* rp = As + (size_t)(wm + i * 16 + lrow) * 128;
            i32x4 lo = *(const i32x4*)(rp + off0);
            i32x4 hi = *(const i32x4*)(rp + off1);
            a[i][0]=lo[0]; a[i][1]=lo[1]; a[i][2]=lo[2]; a[i][3]=lo[3];
            a[i][4]=hi[0]; a[i][5]=hi[1]; a[i][6]=hi[2]; a[i][7]=hi[3];
        }
        #pragma unroll
        for (int i = 0; i < 2; ++i) {
            const u8* rp = Bs + (size_t)(wn + i * 16 + lrow) * 128;
            i32x4 lo = *(const i32x4*)(rp + off0);
            i32x4 hi = *(const i32x4*)(rp + off1);
            b[i][0]=lo[0]; b[i][1]=lo[1]; b[i][2]=lo[2]; b[i][3]=lo[3];
            b[i][4]=hi[0]; b[i][5]=hi[1]; b[i][6]=hi[2]; b[i][7]=hi[3];
        }
        // swapped: lane holds 4 consecutive n at fixed m
        #pragma unroll
        for (int mi = 0; mi < 4; ++mi)
            #pragma unroll
            for (int ni = 0; ni < 2; ++ni)
                acc[mi][ni] = __builtin_amdgcn_mfma_scale_f32_16x16x128_f8f6f4(
                    b[ni], a[mi], acc[mi][ni], 0, 0,
                    0, 0x7f7f7f7f, 0, 0x7f7f7f7f);
        __syncthreads();
    }

    // staged epilogue: pack per-lane 4n values -> LDS (rotated), then coalesced stores
    if (outf8) {
        #pragma unroll
        for (int mi = 0; mi < 4; ++mi) {
            int m = wm + mi * 16 + lrow;
            #pragma unroll
            for (int ni = 0; ni < 2; ++ni) {
                int n0 = wn + ni * 16 + khalf * 4;
                float4 bv = *(const float4*)(bias + bn + n0);
                float w[4];
                w[0] = acc[mi][ni][0] * descale + bv.x;
                w[1] = acc[mi][ni][1] * descale + bv.y;
                w[2] = acc[mi][ni][2] * descale + bv.z;
                w[3] = acc[mi][ni][3] * descale + bv.w;
                if (relu) {
                    w[0] = fmaxf(w[0], 0.f); w[1] = fmaxf(w[1], 0.f);
                    w[2] = fmaxf(w[2], 0.f); w[3] = fmaxf(w[3], 0.f);
                }
                w[0] *= oscale; w[1] *= oscale; w[2] *= oscale; w[3] *= oscale;
                *(u32*)&smem[(size_t)m * 128 + ((n0 + (m & 7) * 16) & 127)] = pk4fp8(w);
            }
        }
        __syncthreads();
        #pragma unroll
        for (int p = 0; p < 2; ++p) {
            int c = tid + p * 512;
            int row = c >> 3;
            int g0 = (c & 7) * 16;
            uint4 v = *(const uint4*)&smem[(size_t)row * 128 + ((g0 + (row & 7) * 16) & 127)];
            *(uint4*)&outf8[(size_t)(bm + row) * Nout + bn + g0] = v;
        }
    } else {
        short* Es = (short*)smem;   // [128][128] shorts = 32 KB, rows rotated by (r&7)*16B
        #pragma unroll
        for (int mi = 0; mi < 4; ++mi) {
            int m = wm + mi * 16 + lrow;
            #pragma unroll
            for (int ni = 0; ni < 2; ++ni) {
                int n0 = wn + ni * 16 + khalf * 4;
                float4 bv = *(const float4*)(bias + bn + n0);
                union { short s[4]; uint2 u; } pk;
                pk.s[0] = f2s(acc[mi][ni][0] * descale + bv.x);
                pk.s[1] = f2s(acc[mi][ni][1] * descale + bv.y);
                pk.s[2] = f2s(acc[mi][ni][2] * descale + bv.z);
                pk.s[3] = f2s(acc[mi][ni][3] * descale + bv.w);
                *(uint2*)&Es[(size_t)m * 128 + ((n0 + (m & 7) * 8) & 127)] = pk.u;
            }
        }
        __syncthreads();
        #pragma unroll
        for (int p = 0; p < 4; ++p) {
            int c = tid + p * 512;
            int row = c >> 4;
            int g0 = (c & 15) * 16;   // byte offset in 256B row
            uint4 v = *(const uint4*)&smem[(size_t)row * 256 + ((g0 + (row & 7) * 16) & 255)];
            *(uint4*)((u8*)outb + ((size_t)(bm + row) * Nout + bn) * 2 + g0) = v;
        }
    }
}

// ---------------- LM head (qkv-proven BK=64 skeleton) + fused CE loss + grid loss finish
__global__ __launch_bounds__(512)
void lm_loss_kernel(const bf16* __restrict__ A, const bf16* __restrict__ Bt,
                    const float* __restrict__ bias, const int* __restrict__ targets,
                    float* __restrict__ outf, float* __restrict__ lossbuf,
                    float* __restrict__ out_loss) {
    __shared__ __align__(16) u8 As[16384];   // [128 rows][128B], row r rotated by (r&7)*16B
    __shared__ __align__(16) u8 Bs[16384];
    __shared__ float Ls[128][66];
    __shared__ float red[128];
    int tid  = threadIdx.x;
    int lane = tid & 63;
    int wave = tid >> 6;
    int bm = blockIdx.x * 128;
    int wm = (wave & 1) * 64;
    int wn = (wave >> 1) * 32;
    int lrow  = lane & 15;
    int khalf = lane >> 4;

    int r0 = tid >> 3;
    int s0 = (((tid & 7) * 16) - (r0 & 7) * 16) & 127;
    int c1 = tid + 512;
    int r1 = c1 >> 3;
    int s1 = (((c1 & 7) * 16) - (r1 & 7) * 16) & 127;
    const u8* ab = (const u8*)A;
    const u8* bb = (const u8*)Bt;
    long gA0 = (long)(bm + r0) * 768 + s0;
    long gA1 = (long)(bm + r1) * 768 + s1;
    long gB0 = (long)r0 * 768 + s0;
    long gB1 = (long)r1 * 768 + s1;
    int ro = (lrow & 7) * 16;

    f32x4 acc[4][2] = {};
    for (int k0 = 0; k0 < 768; k0 += 128) {            // k0 = byte offset within 768B row
        glds16(ab + gA0 + k0, As + (size_t)tid * 16);
        glds16(ab + gA1 + k0, As + (size_t)c1 * 16);
        glds16(bb + gB0 + k0, Bs + (size_t)tid * 16);
        glds16(bb + gB1 + k0, Bs + (size_t)c1 * 16);
        __syncthreads();
        #pragma unroll
        for (int ks = 0; ks < 2; ++ks) {
            int off = (ks * 64 + khalf * 16 + ro) & 127;
            bf16x8 af[4], bff[2];
            #pragma unroll
            for (int i = 0; i < 4; ++i)
                af[i] = *(const bf16x8*)&As[(size_t)(wm + i * 16 + lrow) * 128 + off];
            #pragma unroll
            for (int i = 0; i < 2; ++i)
                bff[i] = *(const bf16x8*)&Bs[(size_t)(wn + i * 16 + lrow) * 128 + off];
            #pragma unroll
            for (int mi = 0; mi < 4; ++mi)
                #pragma unroll
                for (int ni = 0; ni < 2; ++ni)
                    acc[mi][ni] = __builtin_amdgcn_mfma_f32_16x16x32_bf16(af[mi], bff[ni], acc[mi][ni], 0, 0, 0);
        }
        __syncthreads();
    }

    #pragma unroll
    for (int ni = 0; ni < 2; ++ni) {
        int col = wn + ni * 16 + lrow;
        if (col >= VOC) continue;
        float bv = bias[col];
        #pragma unroll
        for (int mi = 0; mi < 4; ++mi) {
            int lr = wm + mi * 16 + khalf * 4;
            #pragma unroll
            for (int r = 0; r < 4; ++r) {
                float v = acc[mi][ni][r] + bv;
                outf[(size_t)(bm + lr + r) * VOC + col] = v;
                Ls[lr + r][col] = v;
            }
        }
    }
    __syncthreads();

    if (tid < 128) {
        int token = bm + tid;
        int tgt = targets[token];
        float m = -1e30f, s = 0.f;
        #pragma unroll 8
        for (int c = 0; c < VOC; ++c) {
            float v = Ls[tid][c];
            float mn = fmaxf(m, v);
            s = s * __expf(m - mn) + __expf(v - mn);
            m = mn;
        }
        red[tid] = m + logf(s) - Ls[tid][tgt];
    }
    __syncthreads();
    if (tid < 64) {
        float s = red[tid] + red[tid + 64];
        #pragma unroll
        for (int off = 32; off > 0; off >>= 1) s += __shfl_xor(s, off);
        if (tid == 0) {
            atomicAdd(&lossbuf[0], s);
            __threadfence();
            int done = atomicAdd(&((int*)lossbuf)[1], 1);
            if (done == (NTOK / 128) - 1) {     // last block
                __threadfence();
                float total = atomicAdd(&lossbuf[0], 0.0f);
                out_loss[0] = total / (float)NTOK;
            }
        }
    }
}

extern "C" void kernel_launch(void* const* d_in, const int* in_sizes, int n_in,
                              void* d_out, int out_size, void* d_ws, size_t ws_size,
                              hipStream_t stream) {
    const int*   idx     = (const int*)  d_in[0];
    const int*   targets = (const int*)  d_in[1];
    const float* tok_emb = (const float*)d_in[2];
    const float* pos_emb = (const float*)d_in[3];
    const float* Wq      = (const float*)d_in[4];
    const float* Wk      = (const float*)d_in[5];
    const float* Wv      = (const float*)d_in[6];
    const float* Wproj   = (const float*)d_in[7];
    const float* bproj   = (const float*)d_in[8];
    const float* W1      = (const float*)d_in[9];
    const float* b1      = (const float*)d_in[10];
    const float* W2      = (const float*)d_in[11];
    const float* b2      = (const float*)d_in[12];
    const float* Wlm     = (const float*)d_in[13];
    const float* blm     = (const float*)d_in[14];

    char* ws = (char*)d_ws;
    bf16*  WprojT = (bf16*) (ws + 0);                       // 24576 B
    float* qkvbuf = (float*)(ws + 25165824);                // 9437184 B
    bf16*  attnT  = (bf16*) (ws + 34603008);                // 2097152 B
    bf16*  xtab   = (bf16*) (ws + 37748736);                // 12779520 B
    u8*    h1f8   = (u8*)   (ws + 62914560);                // 50331648 B
    bf16*  x3     = (bf16*) (ws + 163577856);               // 25165824 B
    float* lossbuf= (float*)(ws + 188743680);               // [0]=sum, [1]=counter
    u8*    W1P    = (u8*)   (ws + 188874752);               // 589824 B (frag-major)
    u8*    W2f8   = (u8*)   (ws + 190054400);               // 589824 B (row-major)
    bf16*  WqkvT  = (bf16*) (ws + 191234048);               // 98304 B
    bf16*  WlmT   = (bf16*) (ws + 191332352);               // 98304 B

    float* out_logits = (float*)d_out;                      // [32768*65] f32
    float* out_loss   = out_logits + (size_t)NTOK * VOC;    // [1]

    pack_all_kernel<<<1312 + XROWS / 4, 256, 0, stream>>>(
        Wq, Wk, Wv, Wlm, Wproj, W1, W2, tok_emb, pos_emb,
        WqkvT, WlmT, WprojT, W1P, W2f8, xtab, lossbuf);

    // 64-token strips -> grid 512 -> 2 blocks/CU co-residency
    qkv_gather_kernel<<<NTOK / 64, 512, 0, stream>>>(idx, xtab, WqkvT, qkvbuf);
    attn_kernel<<<NB * NH, T_SEQ, 0, stream>>>(qkvbuf, attnT);

    // proj + FF1 fused: attnT -> h1f8 (x2 in LDS; W1 streams from L2), grid 512
    ff1_kernel<<<NTOK / 64, 512, 0, stream>>>(attnT, WprojT, bproj, W1P, b1, h1f8);

    // FF2: fp8 [32768,1536] @ fp8 [1536->384] + b2 -> x3 bf16. NT=3. (round-0-proven kernel)
    gemm_fp8_kernel<<<(NTOK / 128) * (C_EMB / 128), 512, 0, stream>>>(h1f8, W2f8, b2,
                                                                      x3, nullptr,
                                                                      FF2_DESCALE, 1.0f,
                                                                      NTOK, FFDIM, C_EMB, C_EMB / 128, 0);

    // LM head + fused loss + grid loss finish
    lm_loss_kernel<<<NTOK / 128, 512, 0, stream>>>(x3, WlmT, blm, targets,
                                                   out_logits, lossbuf, out_loss);
}